// Round 1
// baseline (1891.964 us; speedup 1.0000x reference)
//
#include <hip/hip_runtime.h>

// ---------------------------------------------------------------------------
// Child-Sum TreeLSTM, complete binary tree, level-wise bottom-up.
// Per level (L nodes at s=2^d-1):
//   iou = Wioux@x + Wiouh@(h1+h2) + bioux          (768 outputs)
//   f_k = sigmoid(Wfx@x + Wfh@h_k + bfx + fb)      (256 outputs, k=1,2)
//   c = sig(i)*tanh(u) + f1*c1 + f2*c2 ; h = sig(o)*tanh(c)
// Leaves: h1=h2=c1=c2=0 -> iou only (K=256), c = sig(i)*tanh(u).
//
// MFMA 16x16x32 bf16. A-frag: A[lane%16][ (lane/16)*8 + e ]   (node rows)
//                     B-frag: B[(lane/16)*8+e][lane%16] = W[col_row][k]
//                     D:      row=(lane>>4)*4+r, col=lane&15   (guide-verified)
// ---------------------------------------------------------------------------

typedef __attribute__((ext_vector_type(8))) short bf16x8;
typedef __attribute__((ext_vector_type(4))) float f32x4;
typedef __attribute__((ext_vector_type(4))) unsigned short us4;

#define LSTR 264  // 256 + 8 bf16 pad -> row stride 528B, ds_read_b128 <=2-way conflict

__device__ __forceinline__ unsigned short f2b(float f) {
  unsigned int u = __builtin_bit_cast(unsigned int, f);
  u = u + 0x7FFFu + ((u >> 16) & 1u);   // RNE
  return (unsigned short)(u >> 16);
}

__device__ __forceinline__ float sigm(float x) { return 1.0f / (1.0f + __expf(-x)); }

// Convert the four weight matrices to bf16, packed contiguously in ws.
__global__ void pack_w(const float* __restrict__ a,  // Wioux 768x256
                       const float* __restrict__ b,  // Wiouh 768x256
                       const float* __restrict__ c,  // Wfx   256x256
                       const float* __restrict__ d,  // Wfh   256x256
                       unsigned short* __restrict__ out) {
  int i = blockIdx.x * blockDim.x + threadIdx.x;  // 0 .. 524287
  const int A = 768 * 256;
  const int B = A + 768 * 256;
  const int C = B + 256 * 256;
  float v;
  if (i < A)      v = a[i];
  else if (i < B) v = b[i - A];
  else if (i < C) v = c[i - B];
  else            v = d[i - C];
  out[i] = f2b(v);
}

__global__ __launch_bounds__(512) void level_k(
    const float* __restrict__ x_in,            // [N,256] f32
    const unsigned short* __restrict__ Wx,     // bf16 Wioux [768][256]
    const unsigned short* __restrict__ Wh,     // bf16 Wiouh [768][256]
    const unsigned short* __restrict__ Wfxw,   // bf16 Wfx   [256][256]
    const unsigned short* __restrict__ Wfhw,   // bf16 Wfh   [256][256]
    const float* __restrict__ bioux,           // [768]
    const float* __restrict__ bfx,             // [256]
    const float* __restrict__ fb,              // [256]
    float* __restrict__ h_all,                 // d_out + 512, [N][256]
    float* __restrict__ c_all,                 // ws, [N][256]
    float* __restrict__ out0,                  // d_out (h_root | c_root)
    int s, int L, int leaf, int root)
{
  __shared__ unsigned short Xs[16][LSTR];
  __shared__ unsigned short HSs[16][LSTR];
  __shared__ unsigned short H1s[16][LSTR];
  __shared__ unsigned short H2s[16][LSTR];

  const int tid = threadIdx.x;
  const int nb0 = blockIdx.x * 16;

  // ---- stage 16 nodes: x, h1, h2, h1+h2 as bf16 into LDS ----
  for (int idx = tid; idx < 1024; idx += 512) {
    int row = idx >> 6;
    int c4  = (idx & 63) << 2;           // float col, x4
    int node = nb0 + row;
    float4 xv = make_float4(0.f, 0.f, 0.f, 0.f);
    if (node < L) xv = *(const float4*)(x_in + (size_t)(s + node) * 256 + c4);
    us4 px; px[0] = f2b(xv.x); px[1] = f2b(xv.y); px[2] = f2b(xv.z); px[3] = f2b(xv.w);
    *(us4*)(&Xs[row][c4]) = px;
    if (!leaf) {
      float4 h1 = make_float4(0.f,0.f,0.f,0.f), h2 = make_float4(0.f,0.f,0.f,0.f);
      if (node < L) {
        size_t n = (size_t)(s + node);
        h1 = *(const float4*)(h_all + (2*n + 1) * 256 + c4);
        h2 = *(const float4*)(h_all + (2*n + 2) * 256 + c4);
      }
      us4 p1, p2, ps;
      p1[0] = f2b(h1.x); p1[1] = f2b(h1.y); p1[2] = f2b(h1.z); p1[3] = f2b(h1.w);
      p2[0] = f2b(h2.x); p2[1] = f2b(h2.y); p2[2] = f2b(h2.z); p2[3] = f2b(h2.w);
      ps[0] = f2b(h1.x + h2.x); ps[1] = f2b(h1.y + h2.y);
      ps[2] = f2b(h1.z + h2.z); ps[3] = f2b(h1.w + h2.w);
      *(us4*)(&H1s[row][c4]) = p1;
      *(us4*)(&H2s[row][c4]) = p2;
      *(us4*)(&HSs[row][c4]) = ps;
    }
  }
  __syncthreads();

  // ---- MFMA: each wave owns 2 column-tiles (16 cols each) of the 256 gate cols
  const int lane = tid & 63;
  const int w    = tid >> 6;           // 0..7
  const int lm   = lane & 15;          // A row / B col within tile
  const int kg   = lane >> 4;          // 0..3
  const int koff = kg * 8;

  const f32x4 zero = {0.f, 0.f, 0.f, 0.f};
  f32x4 acc_i[2]  = {zero, zero};
  f32x4 acc_o[2]  = {zero, zero};
  f32x4 acc_u[2]  = {zero, zero};
  f32x4 acc_f1[2] = {zero, zero};
  f32x4 acc_f2[2] = {zero, zero};
  const int ct0 = w * 2;

  // x region: K = 256
  for (int kt = 0; kt < 8; ++kt) {
    const int kx = kt * 32 + koff;
    bf16x8 ax = *(const bf16x8*)(&Xs[lm][kx]);
    #pragma unroll
    for (int t = 0; t < 2; ++t) {
      const int n = (ct0 + t) * 16 + lm;
      const size_t wro = (size_t)n * 256 + kx;
      bf16x8 bi = *(const bf16x8*)(Wx + wro);
      bf16x8 bo = *(const bf16x8*)(Wx + wro + 256 * 256);
      bf16x8 bu = *(const bf16x8*)(Wx + wro + 512 * 256);
      acc_i[t] = __builtin_amdgcn_mfma_f32_16x16x32_bf16(ax, bi, acc_i[t], 0, 0, 0);
      acc_o[t] = __builtin_amdgcn_mfma_f32_16x16x32_bf16(ax, bo, acc_o[t], 0, 0, 0);
      acc_u[t] = __builtin_amdgcn_mfma_f32_16x16x32_bf16(ax, bu, acc_u[t], 0, 0, 0);
      if (!leaf) {
        bf16x8 bf = *(const bf16x8*)(Wfxw + wro);
        acc_f1[t] = __builtin_amdgcn_mfma_f32_16x16x32_bf16(ax, bf, acc_f1[t], 0, 0, 0);
        acc_f2[t] = __builtin_amdgcn_mfma_f32_16x16x32_bf16(ax, bf, acc_f2[t], 0, 0, 0);
      }
    }
  }
  // h region: K = 256 (hsum for iou; h1/h2 for f gates)
  if (!leaf) {
    for (int kt = 0; kt < 8; ++kt) {
      const int kx = kt * 32 + koff;
      bf16x8 ahs = *(const bf16x8*)(&HSs[lm][kx]);
      bf16x8 ah1 = *(const bf16x8*)(&H1s[lm][kx]);
      bf16x8 ah2 = *(const bf16x8*)(&H2s[lm][kx]);
      #pragma unroll
      for (int t = 0; t < 2; ++t) {
        const int n = (ct0 + t) * 16 + lm;
        const size_t wro = (size_t)n * 256 + kx;
        bf16x8 bi = *(const bf16x8*)(Wh + wro);
        bf16x8 bo = *(const bf16x8*)(Wh + wro + 256 * 256);
        bf16x8 bu = *(const bf16x8*)(Wh + wro + 512 * 256);
        acc_i[t] = __builtin_amdgcn_mfma_f32_16x16x32_bf16(ahs, bi, acc_i[t], 0, 0, 0);
        acc_o[t] = __builtin_amdgcn_mfma_f32_16x16x32_bf16(ahs, bo, acc_o[t], 0, 0, 0);
        acc_u[t] = __builtin_amdgcn_mfma_f32_16x16x32_bf16(ahs, bu, acc_u[t], 0, 0, 0);
        bf16x8 bf = *(const bf16x8*)(Wfhw + wro);
        acc_f1[t] = __builtin_amdgcn_mfma_f32_16x16x32_bf16(ah1, bf, acc_f1[t], 0, 0, 0);
        acc_f2[t] = __builtin_amdgcn_mfma_f32_16x16x32_bf16(ah2, bf, acc_f2[t], 0, 0, 0);
      }
    }
  }

  // ---- epilogue: all 5 gate pre-activations for (node m, col) live in-lane ----
  #pragma unroll
  for (int t = 0; t < 2; ++t) {
    const int colc = (ct0 + t) * 16 + lm;
    const float bi_ = bioux[colc];
    const float bo_ = bioux[256 + colc];
    const float bu_ = bioux[512 + colc];
    const float bf_ = leaf ? 0.f : (bfx[colc] + fb[colc]);
    #pragma unroll
    for (int r = 0; r < 4; ++r) {
      const int m = kg * 4 + r;
      const int node = nb0 + m;
      if (node >= L) continue;
      const size_t n = (size_t)(s + node);
      const float ig = sigm(acc_i[t][r] + bi_);
      const float og = sigm(acc_o[t][r] + bo_);
      const float ug = tanhf(acc_u[t][r] + bu_);
      float cv;
      if (leaf) {
        cv = ig * ug;
      } else {
        const float f1 = sigm(acc_f1[t][r] + bf_);
        const float f2 = sigm(acc_f2[t][r] + bf_);
        const float c1 = c_all[(2*n + 1) * 256 + colc];
        const float c2 = c_all[(2*n + 2) * 256 + colc];
        cv = ig * ug + f1 * c1 + f2 * c2;
      }
      const float hv = og * tanhf(cv);
      h_all[n * 256 + colc] = hv;
      c_all[n * 256 + colc] = cv;
      if (root) { out0[colc] = hv; out0[256 + colc] = cv; }
    }
  }
}

extern "C" void kernel_launch(void* const* d_in, const int* in_sizes, int n_in,
                              void* d_out, int out_size, void* d_ws, size_t ws_size,
                              hipStream_t stream) {
  const float* inputs = (const float*)d_in[0];
  const float* Wioux  = (const float*)d_in[1];
  const float* bioux  = (const float*)d_in[2];
  const float* Wiouh  = (const float*)d_in[3];
  const float* Wfx    = (const float*)d_in[4];
  const float* bfx    = (const float*)d_in[5];
  const float* Wfh    = (const float*)d_in[6];
  const float* fb     = (const float*)d_in[7];

  const int N = in_sizes[0] / 256;       // 262143
  int depth = 0;
  while (((1 << depth) - 1) < N) ++depth;  // 18

  float* out   = (float*)d_out;
  float* h_all = out + 512;              // [N][256]
  float* c_all = (float*)d_ws;           // [N][256] f32 scratch
  unsigned short* wb = (unsigned short*)((char*)d_ws + (size_t)N * 256 * 4);

  pack_w<<<2048, 256, 0, stream>>>(Wioux, Wiouh, Wfx, Wfh, wb);

  const unsigned short* pWx  = wb;                       // Wioux
  const unsigned short* pWh  = wb + 768 * 256;           // Wiouh
  const unsigned short* pWfx = wb + 2 * 768 * 256;       // Wfx
  const unsigned short* pWfh = wb + 2 * 768 * 256 + 256 * 256;  // Wfh

  for (int d = depth - 1; d >= 0; --d) {
    const int L = 1 << d;
    const int s = L - 1;
    const int blocks = (L + 15) / 16;
    level_k<<<blocks, 512, 0, stream>>>(inputs, pWx, pWh, pWfx, pWfh,
                                        bioux, bfx, fb, h_all, c_all, out,
                                        s, L, (d == depth - 1) ? 1 : 0, (d == 0) ? 1 : 0);
  }
}

// Round 2
// 1378.687 us; speedup vs baseline: 1.3723x; 1.3723x over previous
//
#include <hip/hip_runtime.h>

// ---------------------------------------------------------------------------
// Child-Sum TreeLSTM, complete binary tree, level-wise bottom-up, bf16 MFMA.
// Round 2: M-tile 32 (2 row-tiles x 2 col-tiles per wave -> 2x weight reuse),
// two-pass gate computation to keep VGPR <= 128 -> 2 blocks/CU for overlap.
//
// MFMA 16x16x32 bf16. A-frag: A[lm][kg*8+e], B-frag: B[kg*8+e][lm]=W[col][k]
// D: row=kg*4+r, col=lm (guide-verified layout).
// ---------------------------------------------------------------------------

typedef __attribute__((ext_vector_type(8))) short bf16x8;
typedef __attribute__((ext_vector_type(8))) unsigned short us8;
typedef __attribute__((ext_vector_type(4))) float f32x4;

#define LSTR 264   // 256 + 8 bf16 pad (row stride 528 B)
#define MT 32      // nodes per block

__device__ __forceinline__ unsigned short f2b(float f) {
  unsigned int u = __builtin_bit_cast(unsigned int, f);
  u = u + 0x7FFFu + ((u >> 16) & 1u);   // RNE
  return (unsigned short)(u >> 16);
}

__device__ __forceinline__ us8 pack8(float4 a, float4 b) {
  us8 r;
  r[0] = f2b(a.x); r[1] = f2b(a.y); r[2] = f2b(a.z); r[3] = f2b(a.w);
  r[4] = f2b(b.x); r[5] = f2b(b.y); r[6] = f2b(b.z); r[7] = f2b(b.w);
  return r;
}

__device__ __forceinline__ float sigm(float x) { return 1.0f / (1.0f + __expf(-x)); }
__device__ __forceinline__ float tanh_f(float x) { return 2.0f / (1.0f + __expf(-2.0f * x)) - 1.0f; }

__global__ void pack_w(const float* __restrict__ a,  // Wioux 768x256
                       const float* __restrict__ b,  // Wiouh 768x256
                       const float* __restrict__ c,  // Wfx   256x256
                       const float* __restrict__ d,  // Wfh   256x256
                       unsigned short* __restrict__ out) {
  int i = blockIdx.x * blockDim.x + threadIdx.x;  // 0 .. 524287
  const int A = 768 * 256;
  const int B = A + 768 * 256;
  const int C = B + 256 * 256;
  float v;
  if (i < A)      v = a[i];
  else if (i < B) v = b[i - A];
  else if (i < C) v = c[i - B];
  else            v = d[i - C];
  out[i] = f2b(v);
}

__global__ __launch_bounds__(512, 4) void level_k(
    const float* __restrict__ x_in,
    const unsigned short* __restrict__ Wx,     // bf16 Wioux [768][256]
    const unsigned short* __restrict__ Wh,     // bf16 Wiouh [768][256]
    const unsigned short* __restrict__ Wfxw,   // bf16 Wfx   [256][256]
    const unsigned short* __restrict__ Wfhw,   // bf16 Wfh   [256][256]
    const float* __restrict__ bioux,
    const float* __restrict__ bfx,
    const float* __restrict__ fb,
    float* __restrict__ h_all,                 // d_out + 512
    float* __restrict__ c_all,                 // ws
    float* __restrict__ out0,                  // d_out
    int s, int L, int leaf, int root)
{
  extern __shared__ unsigned short sm[];
  unsigned short* Xs  = sm;                       // [MT][LSTR]
  unsigned short* HSs = sm + MT * LSTR;
  unsigned short* H1s = sm + 2 * MT * LSTR;
  unsigned short* H2s = sm + 3 * MT * LSTR;

  const int tid = threadIdx.x;
  const int nb0 = blockIdx.x * MT;

  // ---- stage MT nodes: x (and h1, h2, h1+h2) as bf16 into LDS ----
  #pragma unroll
  for (int it = 0; it < 2; ++it) {
    const int gl  = tid + it * 512;        // granule id, 0..1023
    const int row = gl >> 5;
    const int g   = gl & 31;
    const int col = g * 8;                 // element col (8 per granule)
    const int node = nb0 + row;
    float4 x0 = {0,0,0,0}, x1 = {0,0,0,0};
    if (node < L) {
      const float* p = x_in + (size_t)(s + node) * 256 + col;
      x0 = *(const float4*)p; x1 = *(const float4*)(p + 4);
    }
    *(us8*)(Xs + row * LSTR + col) = pack8(x0, x1);
    if (!leaf) {
      float4 a0 = {0,0,0,0}, a1 = {0,0,0,0}, b0 = {0,0,0,0}, b1 = {0,0,0,0};
      if (node < L) {
        const size_t n = (size_t)(s + node);
        const float* p1 = h_all + (2 * n + 1) * 256 + col;
        const float* p2 = h_all + (2 * n + 2) * 256 + col;
        a0 = *(const float4*)p1; a1 = *(const float4*)(p1 + 4);
        b0 = *(const float4*)p2; b1 = *(const float4*)(p2 + 4);
      }
      *(us8*)(H1s + row * LSTR + col) = pack8(a0, a1);
      *(us8*)(H2s + row * LSTR + col) = pack8(b0, b1);
      float4 s0, s1;
      s0.x = a0.x + b0.x; s0.y = a0.y + b0.y; s0.z = a0.z + b0.z; s0.w = a0.w + b0.w;
      s1.x = a1.x + b1.x; s1.y = a1.y + b1.y; s1.z = a1.z + b1.z; s1.w = a1.w + b1.w;
      *(us8*)(HSs + row * LSTR + col) = pack8(s0, s1);
    }
  }
  __syncthreads();

  const int lane = tid & 63;
  const int w    = tid >> 6;          // 0..7
  const int lm   = lane & 15;
  const int kg   = lane >> 4;
  const int koff = kg * 8;
  const int n0   = (w * 2) * 16 + lm; // W row (output col) for t=0

  const f32x4 zero = {0.f, 0.f, 0.f, 0.f};
  f32x4 ai[2][2] = {{zero, zero}, {zero, zero}};
  f32x4 ao[2][2] = {{zero, zero}, {zero, zero}};
  f32x4 au[2][2] = {{zero, zero}, {zero, zero}};

  // ---- pass 1: i, o, u  (x@Wioux^T and hsum@Wiouh^T) ----
  #pragma unroll 2
  for (int kt = 0; kt < 8; ++kt) {
    const int kx = kt * 32 + koff;
    bf16x8 ax0 = *(const bf16x8*)(Xs + lm * LSTR + kx);
    bf16x8 ax1 = *(const bf16x8*)(Xs + (16 + lm) * LSTR + kx);
    #pragma unroll
    for (int t = 0; t < 2; ++t) {
      const unsigned short* wp = Wx + (size_t)(n0 + t * 16) * 256 + kx;
      bf16x8 bi = *(const bf16x8*)wp;
      bf16x8 bo = *(const bf16x8*)(wp + 65536);
      bf16x8 bu = *(const bf16x8*)(wp + 131072);
      ai[0][t] = __builtin_amdgcn_mfma_f32_16x16x32_bf16(ax0, bi, ai[0][t], 0, 0, 0);
      ai[1][t] = __builtin_amdgcn_mfma_f32_16x16x32_bf16(ax1, bi, ai[1][t], 0, 0, 0);
      ao[0][t] = __builtin_amdgcn_mfma_f32_16x16x32_bf16(ax0, bo, ao[0][t], 0, 0, 0);
      ao[1][t] = __builtin_amdgcn_mfma_f32_16x16x32_bf16(ax1, bo, ao[1][t], 0, 0, 0);
      au[0][t] = __builtin_amdgcn_mfma_f32_16x16x32_bf16(ax0, bu, au[0][t], 0, 0, 0);
      au[1][t] = __builtin_amdgcn_mfma_f32_16x16x32_bf16(ax1, bu, au[1][t], 0, 0, 0);
    }
    if (!leaf) {
      bf16x8 as0 = *(const bf16x8*)(HSs + lm * LSTR + kx);
      bf16x8 as1 = *(const bf16x8*)(HSs + (16 + lm) * LSTR + kx);
      #pragma unroll
      for (int t = 0; t < 2; ++t) {
        const unsigned short* wp = Wh + (size_t)(n0 + t * 16) * 256 + kx;
        bf16x8 bi = *(const bf16x8*)wp;
        bf16x8 bo = *(const bf16x8*)(wp + 65536);
        bf16x8 bu = *(const bf16x8*)(wp + 131072);
        ai[0][t] = __builtin_amdgcn_mfma_f32_16x16x32_bf16(as0, bi, ai[0][t], 0, 0, 0);
        ai[1][t] = __builtin_amdgcn_mfma_f32_16x16x32_bf16(as1, bi, ai[1][t], 0, 0, 0);
        ao[0][t] = __builtin_amdgcn_mfma_f32_16x16x32_bf16(as0, bo, ao[0][t], 0, 0, 0);
        ao[1][t] = __builtin_amdgcn_mfma_f32_16x16x32_bf16(as1, bo, ao[1][t], 0, 0, 0);
        au[0][t] = __builtin_amdgcn_mfma_f32_16x16x32_bf16(as0, bu, au[0][t], 0, 0, 0);
        au[1][t] = __builtin_amdgcn_mfma_f32_16x16x32_bf16(as1, bu, au[1][t], 0, 0, 0);
      }
    }
  }

  // ---- intermediate: og, i*u (frees the iou accumulators) ----
  f32x4 og[2][2], iu[2][2];
  #pragma unroll
  for (int t = 0; t < 2; ++t) {
    const int colc = n0 + t * 16;
    const float bi_ = bioux[colc];
    const float bo_ = bioux[256 + colc];
    const float bu_ = bioux[512 + colc];
    #pragma unroll
    for (int rt = 0; rt < 2; ++rt) {
      #pragma unroll
      for (int rr = 0; rr < 4; ++rr) {
        const float ig = sigm(ai[rt][t][rr] + bi_);
        const float ug = tanh_f(au[rt][t][rr] + bu_);
        og[rt][t][rr] = sigm(ao[rt][t][rr] + bo_);
        iu[rt][t][rr] = ig * ug;
      }
    }
  }

  // ---- pass 2: forget gates f1, f2 (x@Wfx^T shared; h1/h2 @ Wfh^T) ----
  f32x4 f1[2][2] = {{zero, zero}, {zero, zero}};
  f32x4 f2[2][2] = {{zero, zero}, {zero, zero}};
  if (!leaf) {
    #pragma unroll 2
    for (int kt = 0; kt < 8; ++kt) {
      const int kx = kt * 32 + koff;
      bf16x8 ax0 = *(const bf16x8*)(Xs + lm * LSTR + kx);
      bf16x8 ax1 = *(const bf16x8*)(Xs + (16 + lm) * LSTR + kx);
      bf16x8 a10 = *(const bf16x8*)(H1s + lm * LSTR + kx);
      bf16x8 a11 = *(const bf16x8*)(H1s + (16 + lm) * LSTR + kx);
      bf16x8 a20 = *(const bf16x8*)(H2s + lm * LSTR + kx);
      bf16x8 a21 = *(const bf16x8*)(H2s + (16 + lm) * LSTR + kx);
      #pragma unroll
      for (int t = 0; t < 2; ++t) {
        const bf16x8 bx = *(const bf16x8*)(Wfxw + (size_t)(n0 + t * 16) * 256 + kx);
        f1[0][t] = __builtin_amdgcn_mfma_f32_16x16x32_bf16(ax0, bx, f1[0][t], 0, 0, 0);
        f1[1][t] = __builtin_amdgcn_mfma_f32_16x16x32_bf16(ax1, bx, f1[1][t], 0, 0, 0);
        f2[0][t] = __builtin_amdgcn_mfma_f32_16x16x32_bf16(ax0, bx, f2[0][t], 0, 0, 0);
        f2[1][t] = __builtin_amdgcn_mfma_f32_16x16x32_bf16(ax1, bx, f2[1][t], 0, 0, 0);
        const bf16x8 bh = *(const bf16x8*)(Wfhw + (size_t)(n0 + t * 16) * 256 + kx);
        f1[0][t] = __builtin_amdgcn_mfma_f32_16x16x32_bf16(a10, bh, f1[0][t], 0, 0, 0);
        f1[1][t] = __builtin_amdgcn_mfma_f32_16x16x32_bf16(a11, bh, f1[1][t], 0, 0, 0);
        f2[0][t] = __builtin_amdgcn_mfma_f32_16x16x32_bf16(a20, bh, f2[0][t], 0, 0, 0);
        f2[1][t] = __builtin_amdgcn_mfma_f32_16x16x32_bf16(a21, bh, f2[1][t], 0, 0, 0);
      }
    }
  }

  // ---- final epilogue ----
  #pragma unroll
  for (int t = 0; t < 2; ++t) {
    const int colc = n0 + t * 16;
    const float bf_ = leaf ? 0.f : (bfx[colc] + fb[colc]);
    #pragma unroll
    for (int rt = 0; rt < 2; ++rt) {
      #pragma unroll
      for (int rr = 0; rr < 4; ++rr) {
        const int m = rt * 16 + kg * 4 + rr;
        const int node = nb0 + m;
        if (node >= L) continue;
        const size_t n = (size_t)(s + node);
        float cv = iu[rt][t][rr];
        if (!leaf) {
          const float fl1 = sigm(f1[rt][t][rr] + bf_);
          const float fl2 = sigm(f2[rt][t][rr] + bf_);
          cv += fl1 * c_all[(2 * n + 1) * 256 + colc]
              + fl2 * c_all[(2 * n + 2) * 256 + colc];
        }
        const float hv = og[rt][t][rr] * tanh_f(cv);
        h_all[n * 256 + colc] = hv;
        c_all[n * 256 + colc] = cv;
        if (root && node == 0) { out0[colc] = hv; out0[256 + colc] = cv; }
      }
    }
  }
}

extern "C" void kernel_launch(void* const* d_in, const int* in_sizes, int n_in,
                              void* d_out, int out_size, void* d_ws, size_t ws_size,
                              hipStream_t stream) {
  const float* inputs = (const float*)d_in[0];
  const float* Wioux  = (const float*)d_in[1];
  const float* bioux  = (const float*)d_in[2];
  const float* Wiouh  = (const float*)d_in[3];
  const float* Wfx    = (const float*)d_in[4];
  const float* bfx    = (const float*)d_in[5];
  const float* Wfh    = (const float*)d_in[6];
  const float* fb     = (const float*)d_in[7];

  const int N = in_sizes[0] / 256;       // 262143
  int depth = 0;
  while (((1 << depth) - 1) < N) ++depth;  // 18

  float* out   = (float*)d_out;
  float* h_all = out + 512;
  float* c_all = (float*)d_ws;
  unsigned short* wb = (unsigned short*)((char*)d_ws + (size_t)N * 256 * 4);

  pack_w<<<2048, 256, 0, stream>>>(Wioux, Wiouh, Wfx, Wfh, wb);

  const unsigned short* pWx  = wb;
  const unsigned short* pWh  = wb + 768 * 256;
  const unsigned short* pWfx = wb + 2 * 768 * 256;
  const unsigned short* pWfh = wb + 2 * 768 * 256 + 256 * 256;

  for (int d = depth - 1; d >= 0; --d) {
    const int L = 1 << d;
    const int s = L - 1;
    const int blocks = (L + MT - 1) / MT;
    const int leaf = (d == depth - 1) ? 1 : 0;
    const size_t shmem = (leaf ? 1 : 4) * (size_t)MT * LSTR * 2;
    level_k<<<blocks, 512, shmem, stream>>>(inputs, pWx, pWh, pWfx, pWfh,
                                            bioux, bfx, fb, h_all, c_all, out,
                                            s, L, leaf, (d == 0) ? 1 : 0);
  }
}